// Round 7
// baseline (763.518 us; speedup 1.0000x reference)
//
#include <hip/hip_runtime.h>

#define NN 100000
#define EE 1600000
#define NG 64
#define NCH 98  // ceil(NN/1024)

// fold-area float offsets
#define OFF_WS0 0
#define OFF_WD0 128
#define OFF_CS0 256
#define OFF_CD0 258
#define OFF_U1  260
#define OFF_C1  324
#define OFF_WS1 512
#define OFF_WD1 768
#define OFF_CS1 1024
#define OFF_CD1 1026
#define OFF_WT0 2048   // transposed We0: [32 out][32 in]
#define FOLD_FLOATS 4096

__device__ __forceinline__ unsigned encm(float f) {
  unsigned u = __float_as_uint(f);
  return (u & 0x80000000u) ? ~u : (u | 0x80000000u);
}
__device__ __forceinline__ float decm(unsigned u) {
  return (u & 0x80000000u) ? __uint_as_float(u & 0x7FFFFFFFu) : __uint_as_float(~u);
}
__device__ __forceinline__ unsigned bf16r(float f) {   // round-to-nearest-even bf16 bits
  unsigned u = __float_as_uint(f);
  return (u + 0x7FFFu + ((u >> 16) & 1u)) >> 16;
}

// ---------------- fold: precompute contracted weight vectors + We0 transpose ----------------
__global__ void fold_k(const float* __restrict__ Wn0, const float* __restrict__ bn0,
                       const float* __restrict__ as0, const float* __restrict__ ad0,
                       const float* __restrict__ We0,
                       const float* __restrict__ We1, const float* __restrict__ be1,
                       const float* __restrict__ ae1,
                       const float* __restrict__ Wn1, const float* __restrict__ bn1,
                       const float* __restrict__ as1, const float* __restrict__ ad1,
                       float* __restrict__ fold) {
  int t = threadIdx.x;  // 256
  for (int i = t; i < 128; i += 256) {        // ws0/wd0: Wn0[2,64,32] . a[2,32]
    int h = i >> 6, d = i & 63;
    float s = 0.f, sd = 0.f;
    for (int k = 0; k < 32; ++k) {
      float w = Wn0[h*2048 + d*32 + k];
      s  += w * as0[h*32 + k];
      sd += w * ad0[h*32 + k];
    }
    fold[OFF_WS0 + i] = s; fold[OFF_WD0 + i] = sd;
  }
  for (int i = t; i < 64; i += 256) {         // u1: We1[2,32,16] . ae1[2,16]
    int h = i >> 5, d = i & 31;
    float s = 0.f;
    for (int k = 0; k < 16; ++k) s += We1[h*512 + d*16 + k] * ae1[h*16 + k];
    fold[OFF_U1 + i] = s;
  }
  for (int i = t; i < 1024; i += 256) {       // WT0[o][d] = We0[o>>4][d][o&15]
    int o = i >> 5, d = i & 31;
    fold[OFF_WT0 + o*32 + d] = We0[(o >> 4)*512 + d*16 + (o & 15)];
  }
  if (t < 256) {                              // ws1/wd1: Wn1[2,128,32] . a[2,32]
    int i = t, h = i >> 7, d = i & 127;
    float s = 0.f, sd = 0.f;
    for (int k = 0; k < 32; ++k) {
      float w = Wn1[h*4096 + d*32 + k];
      s  += w * as1[h*32 + k];
      sd += w * ad1[h*32 + k];
    }
    fold[OFF_WS1 + i] = s; fold[OFF_WD1 + i] = sd;
  }
  if (t < 2) {
    float cs = 0.f, cd = 0.f;
    for (int k = 0; k < 32; ++k) { cs += bn0[t*32+k]*as0[t*32+k]; cd += bn0[t*32+k]*ad0[t*32+k]; }
    fold[OFF_CS0 + t] = cs; fold[OFF_CD0 + t] = cd;
    float c1 = 0.f;
    for (int k = 0; k < 16; ++k) c1 += ae1[t*16+k]*be1[t*16+k];
    fold[OFF_C1 + t] = c1;
    float cs1 = 0.f, cd1 = 0.f;
    for (int k = 0; k < 32; ++k) { cs1 += bn1[t*32+k]*as1[t*32+k]; cd1 += bn1[t*32+k]*ad1[t*32+k]; }
    fold[OFF_CS1 + t] = cs1; fold[OFF_CD1 + t] = cd1;
  }
}

// ---------------- CSR build ----------------
__global__ void count_k(const int* __restrict__ dst, int* __restrict__ cnt) {
  int e = blockIdx.x*256 + threadIdx.x;
  if (e < EE) atomicAdd(&cnt[dst[e]], 1);
}

__global__ __launch_bounds__(1024) void scan1_k(const int* __restrict__ cnt, int* __restrict__ partial) {
  int tid = threadIdx.x, lane = tid & 63, w = tid >> 6;
  int i = blockIdx.x*1024 + tid;
  int v = (i < NN) ? cnt[i] : 0;
  #pragma unroll
  for (int d = 32; d > 0; d >>= 1) v += __shfl_down(v, d);
  __shared__ int wsum[16];
  if (lane == 0) wsum[w] = v;
  __syncthreads();
  if (tid == 0) { int s = 0; for (int q = 0; q < 16; ++q) s += wsum[q]; partial[blockIdx.x] = s; }
}

__global__ void scan2_k(int* __restrict__ partial, int* __restrict__ off) {  // <<<1,1>>>
  int s = 0;
  for (int b = 0; b < NCH; ++b) { int t = partial[b]; partial[b] = s; s += t; }
  off[NN] = s;
}

__global__ __launch_bounds__(1024) void scan3_k(const int* __restrict__ cnt, const int* __restrict__ pbase,
                                                int* __restrict__ off, int* __restrict__ cursor) {
  int tid = threadIdx.x, lane = tid & 63, w = tid >> 6;
  int i = blockIdx.x*1024 + tid;
  int v = (i < NN) ? cnt[i] : 0;
  int x = v;
  #pragma unroll
  for (int d = 1; d < 64; d <<= 1) { int t = __shfl_up(x, d); if (lane >= d) x += t; }
  __shared__ int wsum[16], wbase[16];
  if (lane == 63) wsum[w] = x;
  __syncthreads();
  if (tid == 0) { int s = 0; for (int q = 0; q < 16; ++q) { wbase[q] = s; s += wsum[q]; } }
  __syncthreads();
  int excl = pbase[blockIdx.x] + wbase[w] + x - v;
  if (i < NN) { off[i] = excl; cursor[i] = excl; }
}

__global__ void scatter_k(const int* __restrict__ dst, int* __restrict__ cursor, int* __restrict__ eid) {
  int e = blockIdx.x*256 + threadIdx.x;
  if (e < EE) { int p = atomicAdd(&cursor[dst[e]], 1); eid[p] = e; }
}

// ---------------- layer-0 v-projection: W in VGPRs, 8 nodes/block, bf16 packed output ----------------
__global__ __launch_bounds__(128) void node0v_k(const float* __restrict__ nt, const float* __restrict__ nl,
                                                const float* __restrict__ Wv0, const float* __restrict__ bv0,
                                                unsigned* __restrict__ v0b) {
  int tid = threadIdx.x;
  int h = tid >> 6, k = tid & 63;
  int sl2 = k & 31;
  float w[64];
  #pragma unroll
  for (int d = 0; d < 64; ++d) w[d] = Wv0[h*4096 + d*64 + k];
  float b = bv0[tid];
  int nb = blockIdx.x * 8;   // grid 12500 * 8 = 100000 exactly
  #pragma unroll 1
  for (int r = 0; r < 8; ++r) {
    int n = nb + r;
    const float* nrow = nt + (size_t)n*14;   // uniform addresses -> SGPR loads
    const float* lrow = nl + (size_t)n*50;
    float acc = b;
    #pragma unroll
    for (int d = 0; d < 14; ++d) acc = fmaf(nrow[d], w[d], acc);
    #pragma unroll
    for (int d = 0; d < 50; ++d) acc = fmaf(lrow[d], w[14 + d], acc);
    float p0 = __shfl(acc, 2*sl2);
    float p1 = __shfl(acc, 2*sl2 + 1);
    if (k < 32) v0b[(size_t)n*64 + h*32 + sl2] = bf16r(p0) | (bf16r(p1) << 16);
  }
}

// ---------------- layer-0 z-scalars: one thread per node ----------------
__global__ __launch_bounds__(256) void nodez_k(const float* __restrict__ nt, const float* __restrict__ nl,
                                               const float* __restrict__ fold,
                                               float* __restrict__ zs0, float* __restrict__ zd0) {
  int n = blockIdx.x*256 + threadIdx.x;
  if (n >= NN) return;
  float p0 = 0.f, p1 = 0.f, p2 = 0.f, p3 = 0.f;
  #pragma unroll
  for (int d = 0; d < 64; ++d) {
    float x = (d < 14) ? nt[(size_t)n*14 + d] : nl[(size_t)n*50 + d - 14];
    p0 = fmaf(x, fold[OFF_WS0 + d],      p0);
    p1 = fmaf(x, fold[OFF_WS0 + 64 + d], p1);
    p2 = fmaf(x, fold[OFF_WD0 + d],      p2);
    p3 = fmaf(x, fold[OFF_WD0 + 64 + d], p3);
  }
  zs0[n*2]   = p0 + fold[OFF_CS0];
  zs0[n*2+1] = p1 + fold[OFF_CS0+1];
  zd0[n*2]   = p2 + fold[OFF_CD0];
  zd0[n*2+1] = p3 + fold[OFF_CD0+1];
}

// ---------------- layer-0 edge pass (CSR order): uniform-W MLP, coalesced writes, segmented max ----------------
__global__ __launch_bounds__(256) void edge0_k(const float* __restrict__ xe,
                                               const int* __restrict__ src, const int* __restrict__ dst,
                                               const int* __restrict__ eid,
                                               const float* __restrict__ be0,
                                               const float* __restrict__ ae0, const float* __restrict__ ab0,
                                               const float* __restrict__ fold,
                                               const float* __restrict__ zs0, const float* __restrict__ zd0,
                                               float4* __restrict__ ebuf, float* __restrict__ et1p,
                                               unsigned* __restrict__ menc0) {
  int p = blockIdx.x*256 + threadIdx.x;   // grid exact: EE/256
  int lane = threadIdx.x & 63;
  int e = eid[p];
  int sn = src[e], dn = dst[e];
  const float4* xp = reinterpret_cast<const float4*>(xe + (size_t)e*32);
  float4 xv[8];
  #pragma unroll
  for (int q = 0; q < 8; ++q) xv[q] = xp[q];
  const float* WT = fold + OFF_WT0;
  const float* U1 = fold + OFF_U1;
  float s0 = 0.f, s1 = 0.f, etA = 0.f, etB = 0.f;
  #pragma unroll 4
  for (int o = 0; o < 16; ++o) {          // head 0
    float acc = be0[o];
    #pragma unroll
    for (int q = 0; q < 8; ++q) {         // WT row: wave-uniform -> SGPR loads
      float4 w = *reinterpret_cast<const float4*>(WT + o*32 + q*4);
      acc = fmaf(xv[q].x, w.x, acc); acc = fmaf(xv[q].y, w.y, acc);
      acc = fmaf(xv[q].z, w.z, acc); acc = fmaf(xv[q].w, w.w, acc);
    }
    s0 = fmaf(ae0[o], acc, s0);
    float lz = acc >= 0.f ? acc : 0.01f*acc;
    etA = fmaf(lz, U1[o], etA); etB = fmaf(lz, U1[32 + o], etB);
  }
  #pragma unroll 4
  for (int o = 16; o < 32; ++o) {         // head 1
    float acc = be0[o];
    #pragma unroll
    for (int q = 0; q < 8; ++q) {
      float4 w = *reinterpret_cast<const float4*>(WT + o*32 + q*4);
      acc = fmaf(xv[q].x, w.x, acc); acc = fmaf(xv[q].y, w.y, acc);
      acc = fmaf(xv[q].z, w.z, acc); acc = fmaf(xv[q].w, w.w, acc);
    }
    s1 = fmaf(ae0[o], acc, s1);
    float lz = acc >= 0.f ? acc : 0.01f*acc;
    etA = fmaf(lz, U1[o], etA); etB = fmaf(lz, U1[32 + o], etB);
  }
  float2 zsv = *reinterpret_cast<const float2*>(zs0 + (size_t)sn*2);
  float2 zdv = *reinterpret_cast<const float2*>(zd0 + (size_t)dn*2);
  float l0 = zsv.x + s0 + zdv.x + ab0[0];
  float l1 = zsv.y + s1 + zdv.y + ab0[1];
  l0 = l0 >= 0.f ? l0 : 0.2f*l0;
  l1 = l1 >= 0.f ? l1 : 0.2f*l1;
  ebuf[p] = make_float4(__int_as_float(sn), l0, l1, __int_as_float(dn));
  *reinterpret_cast<float2*>(et1p + (size_t)p*2) =
      make_float2(etA + fold[OFF_C1], etB + fold[OFF_C1+1]);
  // segmented max over sorted dn
  unsigned e0 = encm(l0), e1 = encm(l1);
  #pragma unroll
  for (int o = 1; o < 64; o <<= 1) {      // max idempotent: wave-edge self-return safe
    int pdn = __shfl_down(dn, o);
    unsigned q0 = __shfl_down(e0, o);
    unsigned q1 = __shfl_down(e1, o);
    if (pdn == dn) { e0 = max(e0, q0); e1 = max(e1, q1); }
  }
  int prev = __shfl_up(dn, 1);
  if (lane == 0 || prev != dn) {
    atomicMax(&menc0[(size_t)dn*2],   e0);
    atomicMax(&menc0[(size_t)dn*2+1], e1);
  }
}

// ---------------- layer-0 aggregate: 1 node/wave, lane owns dims (2l,2l+1), no reduction ----------------
__global__ __launch_bounds__(256) void agg0_k(const int* __restrict__ off,
                                              const float4* __restrict__ ebuf,
                                              const unsigned* __restrict__ menc,
                                              const unsigned* __restrict__ v0b,
                                              const float* __restrict__ fold,
                                              unsigned* __restrict__ xb,
                                              float* __restrict__ zs1, float* __restrict__ zd1) {
  int tid = threadIdx.x, w = tid >> 6, lane = tid & 63;
  int n = blockIdx.x*4 + w;            // grid 25000 * 4 waves = 100000 exactly
  int head = lane >> 5;                // lane's dims 2l,2l+1 -> head = l>>5
  int st = off[n], en = off[n+1];
  float m = decm(menc[(size_t)n*2 + head]);
  float alo = 0.f, ahi = 0.f, den = 0.f;
  for (int i = st; i < en; i += 8) {
    float4 eb[8]; unsigned vr[8];
    #pragma unroll
    for (int q = 0; q < 8; ++q) { int j = i + q; eb[q] = ebuf[(j < en) ? j : st]; }
    #pragma unroll
    for (int q = 0; q < 8; ++q) vr[q] = v0b[(size_t)__float_as_int(eb[q].x)*64 + lane];
    #pragma unroll
    for (int q = 0; q < 8; ++q) {
      bool ok = (i + q) < en;
      float s = head ? eb[q].z : eb[q].y;
      float e = ok ? __expf(s - m) : 0.f;
      den += e;
      alo = fmaf(e, __uint_as_float(vr[q] << 16),         alo);
      ahi = fmaf(e, __uint_as_float(vr[q] & 0xFFFF0000u), ahi);
    }
  }
  float inv = 1.f / (den + 1e-9f);
  float xlo = alo*inv, xhi = ahi*inv;
  xlo = xlo >= 0.f ? xlo : 0.01f*xlo;   // inter-layer leaky
  xhi = xhi >= 0.f ? xhi : 0.01f*xhi;
  xb[(size_t)n*64 + lane] = bf16r(xlo) | (bf16r(xhi) << 16);
  // zs1/zd1 scalars: 4 dots over 128 dims, lane holds 2
  const float2* ws1 = reinterpret_cast<const float2*>(fold + OFF_WS1);
  const float2* wd1 = reinterpret_cast<const float2*>(fold + OFF_WD1);
  float2 wa = ws1[lane], wb = ws1[64 + lane], wc = wd1[lane], wd = wd1[64 + lane];
  float p0 = xlo*wa.x + xhi*wa.y;
  float p1 = xlo*wb.x + xhi*wb.y;
  float p2 = xlo*wc.x + xhi*wc.y;
  float p3 = xlo*wd.x + xhi*wd.y;
  #pragma unroll
  for (int o = 32; o > 0; o >>= 1) {
    p0 += __shfl_down(p0, o); p1 += __shfl_down(p1, o);
    p2 += __shfl_down(p2, o); p3 += __shfl_down(p3, o);
  }
  if (lane == 0) {
    zs1[n*2]   = p0 + fold[OFF_CS1];
    zs1[n*2+1] = p1 + fold[OFF_CS1+1];
    zd1[n*2]   = p2 + fold[OFF_CD1];
    zd1[n*2+1] = p3 + fold[OFF_CD1+1];
  }
}

// ---------------- layer-1 node MLP: Wv1 column in VGPRs, one head per wave, 64 nodes/wave ----------------
__global__ __launch_bounds__(256) void node1v_k(const unsigned* __restrict__ xb,
                                                const float* __restrict__ Wv1, const float* __restrict__ bv1,
                                                unsigned* __restrict__ v1b) {
  int tid = threadIdx.x, w = tid >> 6, lane = tid & 63;
  int head = w & 1;
  int chunk = __builtin_amdgcn_readfirstlane(blockIdx.x*2 + (w >> 1));
  int n0 = chunk * 64;
  float wr[128];
  #pragma unroll
  for (int d = 0; d < 128; ++d) wr[d] = Wv1[head*8192 + d*64 + lane];
  float b = bv1[head*64 + lane];
  int sl = lane & 31;
  #pragma unroll 1
  for (int r = 0; r < 64; ++r) {
    int n = n0 + r;
    if (n >= NN) break;
    const unsigned* xr = xb + (size_t)n*64;   // wave-uniform -> s_loads
    float acc = b;
    #pragma unroll
    for (int j = 0; j < 64; ++j) {
      unsigned u = xr[j];
      acc = fmaf(__uint_as_float(u << 16),         wr[2*j],     acc);
      acc = fmaf(__uint_as_float(u & 0xFFFF0000u), wr[2*j + 1], acc);
    }
    float a0 = __shfl(acc, 2*sl), a1 = __shfl(acc, 2*sl + 1);
    if (lane < 32) v1b[(size_t)n*64 + head*32 + sl] = bf16r(a0) | (bf16r(a1) << 16);
  }
}

// ---------------- layer-1 edge logits + fused segmented max (dn from ebuf.w, sorted) ----------------
__global__ __launch_bounds__(256) void edge1_k(float4* __restrict__ ebuf,
                                               const float* __restrict__ zs1, const float* __restrict__ zd1,
                                               const float* __restrict__ et1p, const float* __restrict__ ab1,
                                               unsigned* __restrict__ menc1) {
  int i = blockIdx.x*256 + threadIdx.x;
  int lane = threadIdx.x & 63;
  bool ok = i < EE;
  float l0 = 0.f, l1 = 0.f; int dn = -1;
  if (ok) {
    float4 eb = ebuf[i];
    int sn = __float_as_int(eb.x);
    dn = __float_as_int(eb.w);
    float2 et = *reinterpret_cast<const float2*>(et1p + (size_t)i*2);
    l0 = zs1[sn*2]   + et.x + zd1[dn*2]   + ab1[0];
    l1 = zs1[sn*2+1] + et.y + zd1[dn*2+1] + ab1[1];
    l0 = l0 >= 0.f ? l0 : 0.2f*l0;
    l1 = l1 >= 0.f ? l1 : 0.2f*l1;
    eb.y = l0; eb.z = l1;
    ebuf[i] = eb;
  }
  unsigned e0 = ok ? encm(l0) : 0u;
  unsigned e1 = ok ? encm(l1) : 0u;
  #pragma unroll
  for (int o = 1; o < 64; o <<= 1) {   // max is idempotent: shfl self-return at wave edge is safe
    int pdn = __shfl_down(dn, o);
    unsigned q0 = __shfl_down(e0, o);
    unsigned q1 = __shfl_down(e1, o);
    if (pdn == dn) { e0 = max(e0, q0); e1 = max(e1, q1); }
  }
  int prev = __shfl_up(dn, 1);
  if (ok && (lane == 0 || prev != dn)) {
    atomicMax(&menc1[(size_t)dn*2],   e0);
    atomicMax(&menc1[(size_t)dn*2+1], e1);
  }
}

__global__ void outinit_k(const float* __restrict__ fcb, float* __restrict__ out) {
  int i = threadIdx.x;  // 128
  out[i] = fcb[i & 1];
}

// ---------------- layer-1 aggregate: 1 node/wave, lane owns dims, fused FC ----------------
__global__ __launch_bounds__(256) void agg1_k(const int* __restrict__ off,
                                              const float4* __restrict__ ebuf,
                                              const unsigned* __restrict__ menc,
                                              const unsigned* __restrict__ v1b,
                                              const float* __restrict__ fcW,
                                              float* __restrict__ pnode) {
  int tid = threadIdx.x, w = tid >> 6, lane = tid & 63;
  int n = blockIdx.x*4 + w;
  int head = lane >> 5;
  int st = off[n], en = off[n+1];
  float m = decm(menc[(size_t)n*2 + head]);
  float alo = 0.f, ahi = 0.f, den = 0.f;
  for (int i = st; i < en; i += 8) {
    float4 eb[8]; unsigned vr[8];
    #pragma unroll
    for (int q = 0; q < 8; ++q) { int j = i + q; eb[q] = ebuf[(j < en) ? j : st]; }
    #pragma unroll
    for (int q = 0; q < 8; ++q) vr[q] = v1b[(size_t)__float_as_int(eb[q].x)*64 + lane];
    #pragma unroll
    for (int q = 0; q < 8; ++q) {
      bool ok = (i + q) < en;
      float s = head ? eb[q].z : eb[q].y;
      float e = ok ? __expf(s - m) : 0.f;
      den += e;
      alo = fmaf(e, __uint_as_float(vr[q] << 16),         alo);
      ahi = fmaf(e, __uint_as_float(vr[q] & 0xFFFF0000u), ahi);
    }
  }
  float inv = 1.f / (den + 1e-9f);   // final layer: NO leaky
  float hlo = alo*inv, hhi = ahi*inv;
  const float2* fw2 = reinterpret_cast<const float2*>(fcW);
  float2 f0 = fw2[2*lane], f1 = fw2[2*lane + 1];   // rows 2l, 2l+1 of fcW[128][2]
  float p0 = hlo*f0.x + hhi*f1.x;
  float p1 = hlo*f0.y + hhi*f1.y;
  #pragma unroll
  for (int o = 32; o > 0; o >>= 1) {
    p0 += __shfl_down(p0, o);
    p1 += __shfl_down(p1, o);
  }
  if (lane == 0) {
    pnode[n*2]   = p0;
    pnode[n*2+1] = p1;
  }
}

// ---------------- graph readout: segmented sum over sorted gid, few atomics ----------------
__global__ __launch_bounds__(256) void gsum_k(const float* __restrict__ pnode, const int* __restrict__ gid,
                                              float* __restrict__ out) {
  int n = blockIdx.x*256 + threadIdx.x;
  int lane = threadIdx.x & 63;
  bool ok = n < NN;
  int g = ok ? gid[n] : -1;
  float p0 = ok ? pnode[n*2]   : 0.f;
  float p1 = ok ? pnode[n*2+1] : 0.f;
  #pragma unroll
  for (int o = 1; o < 64; o <<= 1) {
    int pg = __shfl_down(g, o);
    float q0 = __shfl_down(p0, o);
    float q1 = __shfl_down(p1, o);
    if ((lane + o) < 64 && pg == g) { p0 += q0; p1 += q1; }  // clamp: sum is NOT idempotent
  }
  int prev = __shfl_up(g, 1);
  if (ok && (lane == 0 || prev != g)) {
    atomicAdd(&out[g*2],     p0);
    atomicAdd(&out[g*2 + 1], p1);
  }
}

extern "C" void kernel_launch(void* const* d_in, const int* in_sizes, int n_in,
                              void* d_out, int out_size, void* d_ws, size_t ws_size,
                              hipStream_t stream) {
  const float* nt  = (const float*)d_in[0];
  const float* nl  = (const float*)d_in[1];
  const float* xe  = (const float*)d_in[2];
  const int*   src = (const int*)d_in[3];
  const int*   dst = (const int*)d_in[4];
  const int*   gid = (const int*)d_in[5];
  const float* Wn0 = (const float*)d_in[6],  *bn0 = (const float*)d_in[7];
  const float* Wv0 = (const float*)d_in[8],  *bv0 = (const float*)d_in[9];
  const float* We0 = (const float*)d_in[10], *be0 = (const float*)d_in[11];
  const float* as0 = (const float*)d_in[12], *ae0 = (const float*)d_in[13];
  const float* ad0 = (const float*)d_in[14], *ab0 = (const float*)d_in[15];
  const float* Wn1 = (const float*)d_in[16], *bn1 = (const float*)d_in[17];
  const float* Wv1 = (const float*)d_in[18], *bv1 = (const float*)d_in[19];
  const float* We1 = (const float*)d_in[20], *be1 = (const float*)d_in[21];
  const float* as1 = (const float*)d_in[22], *ae1 = (const float*)d_in[23];
  const float* ad1 = (const float*)d_in[24], *ab1 = (const float*)d_in[25];
  const float* fcW = (const float*)d_in[26], *fcb = (const float*)d_in[27];
  float* out = (float*)d_out;

  // workspace layout (floats, then uints, then ints); ~122 MB
  float* fold  = (float*)d_ws;                        // 4096
  float* zs    = fold + FOLD_FLOATS;                  // N*2 (layer0 then layer1)
  float* zd    = zs + (size_t)NN*2;                   // N*2
  unsigned* v0b = (unsigned*)(zd + (size_t)NN*2);     // N*64 u32 (bf16 x2)
  unsigned* v1b = v0b + (size_t)NN*64;                // N*64 u32
  unsigned* xb  = v1b + (size_t)NN*64;                // N*64 u32 (normalized l0 output)
  float* et1p  = (float*)(xb + (size_t)NN*64);        // E*2
  float* ebuff = et1p + (size_t)EE*2;                 // E*4 (float4 per CSR pos)
  unsigned* menc0 = (unsigned*)(ebuff + (size_t)EE*4); // N*2
  unsigned* menc1 = menc0 + (size_t)NN*2;             // N*2
  float* pnode = (float*)(menc1 + (size_t)NN*2);      // N*2
  int* cnt    = (int*)(pnode + (size_t)NN*2);         // N
  int* off    = cnt + NN;                             // N+1
  int* cursor = off + NN + 1;                         // N
  int* eid    = cursor + NN;                          // E
  int* part   = eid + EE;                             // NCH
  float4* ebuf = (float4*)ebuff;

  hipMemsetAsync(cnt, 0, NN*sizeof(int), stream);
  hipMemsetAsync(menc0, 0, (size_t)NN*4*sizeof(unsigned), stream);  // menc0 + menc1
  fold_k<<<1, 256, 0, stream>>>(Wn0, bn0, as0, ad0, We0, We1, be1, ae1, Wn1, bn1, as1, ad1, fold);
  count_k<<<EE/256, 256, 0, stream>>>(dst, cnt);
  scan1_k<<<NCH, 1024, 0, stream>>>(cnt, part);
  scan2_k<<<1, 1, 0, stream>>>(part, off);
  scan3_k<<<NCH, 1024, 0, stream>>>(cnt, part, off, cursor);
  scatter_k<<<EE/256, 256, 0, stream>>>(dst, cursor, eid);
  node0v_k<<<NN/8, 128, 0, stream>>>(nt, nl, Wv0, bv0, v0b);
  nodez_k<<<(NN + 255)/256, 256, 0, stream>>>(nt, nl, fold, zs, zd);
  edge0_k<<<EE/256, 256, 0, stream>>>(xe, src, dst, eid, be0, ae0, ab0, fold, zs, zd, ebuf, et1p, menc0);
  agg0_k<<<NN/4, 256, 0, stream>>>(off, ebuf, menc0, v0b, fold, xb, zs, zd);
  node1v_k<<<(NN + 127)/128, 256, 0, stream>>>(xb, Wv1, bv1, v1b);
  edge1_k<<<EE/256, 256, 0, stream>>>(ebuf, zs, zd, et1p, ab1, menc1);
  outinit_k<<<1, 128, 0, stream>>>(fcb, out);
  agg1_k<<<NN/4, 256, 0, stream>>>(off, ebuf, menc1, v1b, fcW, pnode);
  gsum_k<<<(NN + 255)/256, 256, 0, stream>>>(pnode, gid, out);
}

// Round 8
// 646.573 us; speedup vs baseline: 1.1809x; 1.1809x over previous
//
#include <hip/hip_runtime.h>

#define NN 100000
#define EE 1600000
#define NG 64
#define NCH 98  // ceil(NN/1024)

// fold-area float offsets
#define OFF_WS0 0
#define OFF_WD0 128
#define OFF_CS0 256
#define OFF_CD0 258
#define OFF_U1  260
#define OFF_C1  324
#define OFF_WS1 512
#define OFF_WD1 768
#define OFF_CS1 1024
#define OFF_CD1 1026
#define OFF_WT0 2048   // transposed We0: [32 out][32 in]
#define FOLD_FLOATS 4096

typedef __attribute__((ext_vector_type(8))) short short8;
typedef __attribute__((ext_vector_type(4))) float f32x4;

__device__ __forceinline__ unsigned encm(float f) {
  unsigned u = __float_as_uint(f);
  return (u & 0x80000000u) ? ~u : (u | 0x80000000u);
}
__device__ __forceinline__ float decm(unsigned u) {
  return (u & 0x80000000u) ? __uint_as_float(u & 0x7FFFFFFFu) : __uint_as_float(~u);
}
__device__ __forceinline__ unsigned bf16r(float f) {   // round-to-nearest-even bf16 bits
  unsigned u = __float_as_uint(f);
  return (u + 0x7FFFu + ((u >> 16) & 1u)) >> 16;
}

// ---------------- fold: contracted weight vectors, We0 transpose, Wv1 bf16-transpose ----------------
__global__ void fold_k(const float* __restrict__ Wn0, const float* __restrict__ bn0,
                       const float* __restrict__ as0, const float* __restrict__ ad0,
                       const float* __restrict__ We0,
                       const float* __restrict__ We1, const float* __restrict__ be1,
                       const float* __restrict__ ae1,
                       const float* __restrict__ Wn1, const float* __restrict__ bn1,
                       const float* __restrict__ as1, const float* __restrict__ ad1,
                       const float* __restrict__ Wv1,
                       float* __restrict__ fold, unsigned* __restrict__ w1tw) {
  int t = threadIdx.x;  // 256
  for (int i = t; i < 128; i += 256) {        // ws0/wd0: Wn0[2,64,32] . a[2,32]
    int h = i >> 6, d = i & 63;
    float s = 0.f, sd = 0.f;
    for (int k = 0; k < 32; ++k) {
      float w = Wn0[h*2048 + d*32 + k];
      s  += w * as0[h*32 + k];
      sd += w * ad0[h*32 + k];
    }
    fold[OFF_WS0 + i] = s; fold[OFF_WD0 + i] = sd;
  }
  for (int i = t; i < 64; i += 256) {         // u1: We1[2,32,16] . ae1[2,16]
    int h = i >> 5, d = i & 31;
    float s = 0.f;
    for (int k = 0; k < 16; ++k) s += We1[h*512 + d*16 + k] * ae1[h*16 + k];
    fold[OFF_U1 + i] = s;
  }
  for (int i = t; i < 1024; i += 256) {       // WT0[o][d] = We0[o>>4][d][o&15]
    int o = i >> 5, d = i & 31;
    fold[OFF_WT0 + o*32 + d] = We0[(o >> 4)*512 + d*16 + (o & 15)];
  }
  // w1tw: bf16 W1^T, ushort layout wt[o][d] packed as u32 words: word idx = o*64 + d/2
  for (int i = t; i < 8192; i += 256) {
    int o = i >> 6, dw = i & 63;
    int d0 = 2*dw, d1 = d0 + 1;
    float f0 = Wv1[(o >> 6)*8192 + d0*64 + (o & 63)];
    float f1 = Wv1[(o >> 6)*8192 + d1*64 + (o & 63)];
    w1tw[i] = bf16r(f0) | (bf16r(f1) << 16);
  }
  if (t < 256) {                              // ws1/wd1: Wn1[2,128,32] . a[2,32]
    int i = t, h = i >> 7, d = i & 127;
    float s = 0.f, sd = 0.f;
    for (int k = 0; k < 32; ++k) {
      float w = Wn1[h*4096 + d*32 + k];
      s  += w * as1[h*32 + k];
      sd += w * ad1[h*32 + k];
    }
    fold[OFF_WS1 + i] = s; fold[OFF_WD1 + i] = sd;
  }
  if (t < 2) {
    float cs = 0.f, cd = 0.f;
    for (int k = 0; k < 32; ++k) { cs += bn0[t*32+k]*as0[t*32+k]; cd += bn0[t*32+k]*ad0[t*32+k]; }
    fold[OFF_CS0 + t] = cs; fold[OFF_CD0 + t] = cd;
    float c1 = 0.f;
    for (int k = 0; k < 16; ++k) c1 += ae1[t*16+k]*be1[t*16+k];
    fold[OFF_C1 + t] = c1;
    float cs1 = 0.f, cd1 = 0.f;
    for (int k = 0; k < 32; ++k) { cs1 += bn1[t*32+k]*as1[t*32+k]; cd1 += bn1[t*32+k]*ad1[t*32+k]; }
    fold[OFF_CS1 + t] = cs1; fold[OFF_CD1 + t] = cd1;
  }
}

// ---------------- CSR build ----------------
__global__ void count_k(const int* __restrict__ dst, int* __restrict__ cnt) {
  int e = blockIdx.x*256 + threadIdx.x;
  if (e < EE) atomicAdd(&cnt[dst[e]], 1);
}

__global__ __launch_bounds__(1024) void scan1_k(const int* __restrict__ cnt, int* __restrict__ partial) {
  int tid = threadIdx.x, lane = tid & 63, w = tid >> 6;
  int i = blockIdx.x*1024 + tid;
  int v = (i < NN) ? cnt[i] : 0;
  #pragma unroll
  for (int d = 32; d > 0; d >>= 1) v += __shfl_down(v, d);
  __shared__ int wsum[16];
  if (lane == 0) wsum[w] = v;
  __syncthreads();
  if (tid == 0) { int s = 0; for (int q = 0; q < 16; ++q) s += wsum[q]; partial[blockIdx.x] = s; }
}

__global__ void scan2_k(int* __restrict__ partial, int* __restrict__ off) {  // <<<1,1>>>
  int s = 0;
  for (int b = 0; b < NCH; ++b) { int t = partial[b]; partial[b] = s; s += t; }
  off[NN] = s;
}

__global__ __launch_bounds__(1024) void scan3_k(const int* __restrict__ cnt, const int* __restrict__ pbase,
                                                int* __restrict__ off, int* __restrict__ cursor) {
  int tid = threadIdx.x, lane = tid & 63, w = tid >> 6;
  int i = blockIdx.x*1024 + tid;
  int v = (i < NN) ? cnt[i] : 0;
  int x = v;
  #pragma unroll
  for (int d = 1; d < 64; d <<= 1) { int t = __shfl_up(x, d); if (lane >= d) x += t; }
  __shared__ int wsum[16], wbase[16];
  if (lane == 63) wsum[w] = x;
  __syncthreads();
  if (tid == 0) { int s = 0; for (int q = 0; q < 16; ++q) { wbase[q] = s; s += wsum[q]; } }
  __syncthreads();
  int excl = pbase[blockIdx.x] + wbase[w] + x - v;
  if (i < NN) { off[i] = excl; cursor[i] = excl; }
}

__global__ void scatter_k(const int* __restrict__ dst, int* __restrict__ cursor, int* __restrict__ eid) {
  int e = blockIdx.x*256 + threadIdx.x;
  if (e < EE) { int p = atomicAdd(&cursor[dst[e]], 1); eid[p] = e; }
}

// ---------------- layer-0 v-projection: W in VGPRs, 8 nodes/block, bf16 packed output ----------------
__global__ __launch_bounds__(128) void node0v_k(const float* __restrict__ nt, const float* __restrict__ nl,
                                                const float* __restrict__ Wv0, const float* __restrict__ bv0,
                                                unsigned* __restrict__ v0b) {
  int tid = threadIdx.x;
  int h = tid >> 6, k = tid & 63;
  int sl2 = k & 31;
  float w[64];
  #pragma unroll
  for (int d = 0; d < 64; ++d) w[d] = Wv0[h*4096 + d*64 + k];
  float b = bv0[tid];
  int nb = blockIdx.x * 8;   // grid 12500 * 8 = 100000 exactly
  #pragma unroll 1
  for (int r = 0; r < 8; ++r) {
    int n = nb + r;
    const float* nrow = nt + (size_t)n*14;   // uniform addresses -> SGPR loads
    const float* lrow = nl + (size_t)n*50;
    float acc = b;
    #pragma unroll
    for (int d = 0; d < 14; ++d) acc = fmaf(nrow[d], w[d], acc);
    #pragma unroll
    for (int d = 0; d < 50; ++d) acc = fmaf(lrow[d], w[14 + d], acc);
    float p0 = __shfl(acc, 2*sl2);
    float p1 = __shfl(acc, 2*sl2 + 1);
    if (k < 32) v0b[(size_t)n*64 + h*32 + sl2] = bf16r(p0) | (bf16r(p1) << 16);
  }
}

// ---------------- layer-0 z-scalars: one thread per node ----------------
__global__ __launch_bounds__(256) void nodez_k(const float* __restrict__ nt, const float* __restrict__ nl,
                                               const float* __restrict__ fold,
                                               float* __restrict__ zs0, float* __restrict__ zd0) {
  int n = blockIdx.x*256 + threadIdx.x;
  if (n >= NN) return;
  float p0 = 0.f, p1 = 0.f, p2 = 0.f, p3 = 0.f;
  #pragma unroll
  for (int d = 0; d < 64; ++d) {
    float x = (d < 14) ? nt[(size_t)n*14 + d] : nl[(size_t)n*50 + d - 14];
    p0 = fmaf(x, fold[OFF_WS0 + d],      p0);
    p1 = fmaf(x, fold[OFF_WS0 + 64 + d], p1);
    p2 = fmaf(x, fold[OFF_WD0 + d],      p2);
    p3 = fmaf(x, fold[OFF_WD0 + 64 + d], p3);
  }
  zs0[n*2]   = p0 + fold[OFF_CS0];
  zs0[n*2+1] = p1 + fold[OFF_CS0+1];
  zd0[n*2]   = p2 + fold[OFF_CD0];
  zd0[n*2+1] = p3 + fold[OFF_CD0+1];
}

// ---------------- layer-0 edge pass (CSR order): uniform-W MLP, coalesced writes, segmented max ----------------
__global__ __launch_bounds__(256) void edge0_k(const float* __restrict__ xe,
                                               const int* __restrict__ src, const int* __restrict__ dst,
                                               const int* __restrict__ eid,
                                               const float* __restrict__ be0,
                                               const float* __restrict__ ae0, const float* __restrict__ ab0,
                                               const float* __restrict__ fold,
                                               const float* __restrict__ zs0, const float* __restrict__ zd0,
                                               float4* __restrict__ ebuf, float* __restrict__ et1p,
                                               unsigned* __restrict__ menc0) {
  int p = blockIdx.x*256 + threadIdx.x;   // grid exact: EE/256
  int lane = threadIdx.x & 63;
  int e = eid[p];
  int sn = src[e], dn = dst[e];
  const float4* xp = reinterpret_cast<const float4*>(xe + (size_t)e*32);
  float4 xv[8];
  #pragma unroll
  for (int q = 0; q < 8; ++q) xv[q] = xp[q];
  const float* WT = fold + OFF_WT0;
  const float* U1 = fold + OFF_U1;
  float s0 = 0.f, s1 = 0.f, etA = 0.f, etB = 0.f;
  #pragma unroll 4
  for (int o = 0; o < 16; ++o) {          // head 0
    float acc = be0[o];
    #pragma unroll
    for (int q = 0; q < 8; ++q) {         // WT row: wave-uniform -> SGPR loads
      float4 w = *reinterpret_cast<const float4*>(WT + o*32 + q*4);
      acc = fmaf(xv[q].x, w.x, acc); acc = fmaf(xv[q].y, w.y, acc);
      acc = fmaf(xv[q].z, w.z, acc); acc = fmaf(xv[q].w, w.w, acc);
    }
    s0 = fmaf(ae0[o], acc, s0);
    float lz = acc >= 0.f ? acc : 0.01f*acc;
    etA = fmaf(lz, U1[o], etA); etB = fmaf(lz, U1[32 + o], etB);
  }
  #pragma unroll 4
  for (int o = 16; o < 32; ++o) {         // head 1
    float acc = be0[o];
    #pragma unroll
    for (int q = 0; q < 8; ++q) {
      float4 w = *reinterpret_cast<const float4*>(WT + o*32 + q*4);
      acc = fmaf(xv[q].x, w.x, acc); acc = fmaf(xv[q].y, w.y, acc);
      acc = fmaf(xv[q].z, w.z, acc); acc = fmaf(xv[q].w, w.w, acc);
    }
    s1 = fmaf(ae0[o], acc, s1);
    float lz = acc >= 0.f ? acc : 0.01f*acc;
    etA = fmaf(lz, U1[o], etA); etB = fmaf(lz, U1[32 + o], etB);
  }
  float2 zsv = *reinterpret_cast<const float2*>(zs0 + (size_t)sn*2);
  float2 zdv = *reinterpret_cast<const float2*>(zd0 + (size_t)dn*2);
  float l0 = zsv.x + s0 + zdv.x + ab0[0];
  float l1 = zsv.y + s1 + zdv.y + ab0[1];
  l0 = l0 >= 0.f ? l0 : 0.2f*l0;
  l1 = l1 >= 0.f ? l1 : 0.2f*l1;
  ebuf[p] = make_float4(__int_as_float(sn), l0, l1, __int_as_float(dn));
  *reinterpret_cast<float2*>(et1p + (size_t)p*2) =
      make_float2(etA + fold[OFF_C1], etB + fold[OFF_C1+1]);
  // segmented max over sorted dn
  unsigned e0 = encm(l0), e1 = encm(l1);
  #pragma unroll
  for (int o = 1; o < 64; o <<= 1) {      // max idempotent: wave-edge self-return safe
    int pdn = __shfl_down(dn, o);
    unsigned q0 = __shfl_down(e0, o);
    unsigned q1 = __shfl_down(e1, o);
    if (pdn == dn) { e0 = max(e0, q0); e1 = max(e1, q1); }
  }
  int prev = __shfl_up(dn, 1);
  if (lane == 0 || prev != dn) {
    atomicMax(&menc0[(size_t)dn*2],   e0);
    atomicMax(&menc0[(size_t)dn*2+1], e1);
  }
}

// ---------------- layer-0 aggregate: 1 node/wave, lane owns dims (2l,2l+1), no reduction ----------------
__global__ __launch_bounds__(256) void agg0_k(const int* __restrict__ off,
                                              const float4* __restrict__ ebuf,
                                              const unsigned* __restrict__ menc,
                                              const unsigned* __restrict__ v0b,
                                              const float* __restrict__ fold,
                                              unsigned* __restrict__ xb,
                                              float* __restrict__ zs1, float* __restrict__ zd1) {
  int tid = threadIdx.x, w = tid >> 6, lane = tid & 63;
  int n = blockIdx.x*4 + w;            // grid 25000 * 4 waves = 100000 exactly
  int head = lane >> 5;                // lane's dims 2l,2l+1 -> head = l>>5
  int st = off[n], en = off[n+1];
  float m = decm(menc[(size_t)n*2 + head]);
  float alo = 0.f, ahi = 0.f, den = 0.f;
  for (int i = st; i < en; i += 8) {
    float4 eb[8]; unsigned vr[8];
    #pragma unroll
    for (int q = 0; q < 8; ++q) { int j = i + q; eb[q] = ebuf[(j < en) ? j : st]; }
    #pragma unroll
    for (int q = 0; q < 8; ++q) vr[q] = v0b[(size_t)__float_as_int(eb[q].x)*64 + lane];
    #pragma unroll
    for (int q = 0; q < 8; ++q) {
      bool ok = (i + q) < en;
      float s = head ? eb[q].z : eb[q].y;
      float e = ok ? __expf(s - m) : 0.f;
      den += e;
      alo = fmaf(e, __uint_as_float(vr[q] << 16),         alo);
      ahi = fmaf(e, __uint_as_float(vr[q] & 0xFFFF0000u), ahi);
    }
  }
  float inv = 1.f / (den + 1e-9f);
  float xlo = alo*inv, xhi = ahi*inv;
  xlo = xlo >= 0.f ? xlo : 0.01f*xlo;   // inter-layer leaky
  xhi = xhi >= 0.f ? xhi : 0.01f*xhi;
  xb[(size_t)n*64 + lane] = bf16r(xlo) | (bf16r(xhi) << 16);
  // zs1/zd1 scalars: 4 dots over 128 dims, lane holds 2
  const float2* ws1 = reinterpret_cast<const float2*>(fold + OFF_WS1);
  const float2* wd1 = reinterpret_cast<const float2*>(fold + OFF_WD1);
  float2 wa = ws1[lane], wb = ws1[64 + lane], wc = wd1[lane], wd = wd1[64 + lane];
  float p0 = xlo*wa.x + xhi*wa.y;
  float p1 = xlo*wb.x + xhi*wb.y;
  float p2 = xlo*wc.x + xhi*wc.y;
  float p3 = xlo*wd.x + xhi*wd.y;
  #pragma unroll
  for (int o = 32; o > 0; o >>= 1) {
    p0 += __shfl_down(p0, o); p1 += __shfl_down(p1, o);
    p2 += __shfl_down(p2, o); p3 += __shfl_down(p3, o);
  }
  if (lane == 0) {
    zs1[n*2]   = p0 + fold[OFF_CS1];
    zs1[n*2+1] = p1 + fold[OFF_CS1+1];
    zd1[n*2]   = p2 + fold[OFF_CD1];
    zd1[n*2+1] = p3 + fold[OFF_CD1+1];
  }
}

// ---------------- layer-1 node MLP via MFMA: [N,128]bf16 @ [128,128]bf16 -> v1 bf16 ----------------
// Per wave: one 16-node tile, 8 output tiles x 4 K-steps = 32 v_mfma_f32_16x16x32_bf16.
// A lane layout: row = lane&15, k = 8*(lane>>4)+j (blocked-K). B: col = lane&15, same k.
// C/D: col = lane&15, row = (lane>>4)*4 + reg  [m89-verified].
__global__ __launch_bounds__(256) void node1m_k(const unsigned* __restrict__ xb,
                                                const unsigned* __restrict__ w1tw,
                                                const float* __restrict__ bv1,
                                                unsigned short* __restrict__ v1s) {
  int tid = threadIdx.x, w = tid >> 6, lane = tid & 63;
  int tile = blockIdx.x*4 + w;         // 6250 tiles of 16 nodes
  if (tile >= NN/16) return;
  int row = lane & 15, kg = lane >> 4;
  int n = tile*16 + row;
  short8 a[4];
  #pragma unroll
  for (int ks = 0; ks < 4; ++ks)
    a[ks] = *reinterpret_cast<const short8*>(xb + (size_t)n*64 + ks*16 + kg*4);
  #pragma unroll 2
  for (int t = 0; t < 8; ++t) {
    float bias = bv1[t*16 + row];      // out col o = t*16 + (lane&15); bv1 is [2][64] = [128]
    f32x4 acc = {bias, bias, bias, bias};
    #pragma unroll
    for (int ks = 0; ks < 4; ++ks) {
      short8 b = *reinterpret_cast<const short8*>(w1tw + (size_t)(t*16 + row)*64 + ks*16 + kg*4);
      acc = __builtin_amdgcn_mfma_f32_16x16x32_bf16(a[ks], b, acc, 0, 0, 0);
    }
    int o = t*16 + row;
    #pragma unroll
    for (int r = 0; r < 4; ++r) {
      int nr = tile*16 + kg*4 + r;
      v1s[(size_t)nr*128 + o] = (unsigned short)bf16r(acc[r]);
    }
  }
}

// ---------------- layer-1 edge logits + fused segmented max (dn from ebuf.w, sorted) ----------------
__global__ __launch_bounds__(256) void edge1_k(float4* __restrict__ ebuf,
                                               const float* __restrict__ zs1, const float* __restrict__ zd1,
                                               const float* __restrict__ et1p, const float* __restrict__ ab1,
                                               unsigned* __restrict__ menc1) {
  int i = blockIdx.x*256 + threadIdx.x;
  int lane = threadIdx.x & 63;
  bool ok = i < EE;
  float l0 = 0.f, l1 = 0.f; int dn = -1;
  if (ok) {
    float4 eb = ebuf[i];
    int sn = __float_as_int(eb.x);
    dn = __float_as_int(eb.w);
    float2 et = *reinterpret_cast<const float2*>(et1p + (size_t)i*2);
    l0 = zs1[sn*2]   + et.x + zd1[dn*2]   + ab1[0];
    l1 = zs1[sn*2+1] + et.y + zd1[dn*2+1] + ab1[1];
    l0 = l0 >= 0.f ? l0 : 0.2f*l0;
    l1 = l1 >= 0.f ? l1 : 0.2f*l1;
    eb.y = l0; eb.z = l1;
    ebuf[i] = eb;
  }
  unsigned e0 = ok ? encm(l0) : 0u;
  unsigned e1 = ok ? encm(l1) : 0u;
  #pragma unroll
  for (int o = 1; o < 64; o <<= 1) {   // max is idempotent: shfl self-return at wave edge is safe
    int pdn = __shfl_down(dn, o);
    unsigned q0 = __shfl_down(e0, o);
    unsigned q1 = __shfl_down(e1, o);
    if (pdn == dn) { e0 = max(e0, q0); e1 = max(e1, q1); }
  }
  int prev = __shfl_up(dn, 1);
  if (ok && (lane == 0 || prev != dn)) {
    atomicMax(&menc1[(size_t)dn*2],   e0);
    atomicMax(&menc1[(size_t)dn*2+1], e1);
  }
}

__global__ void outinit_k(const float* __restrict__ fcb, float* __restrict__ out) {
  int i = threadIdx.x;  // 128
  out[i] = fcb[i & 1];
}

// ---------------- layer-1 aggregate: 1 node/wave, lane owns dims, fused FC ----------------
__global__ __launch_bounds__(256) void agg1_k(const int* __restrict__ off,
                                              const float4* __restrict__ ebuf,
                                              const unsigned* __restrict__ menc,
                                              const unsigned* __restrict__ v1b,
                                              const float* __restrict__ fcW,
                                              float* __restrict__ pnode) {
  int tid = threadIdx.x, w = tid >> 6, lane = tid & 63;
  int n = blockIdx.x*4 + w;
  int head = lane >> 5;
  int st = off[n], en = off[n+1];
  float m = decm(menc[(size_t)n*2 + head]);
  float alo = 0.f, ahi = 0.f, den = 0.f;
  for (int i = st; i < en; i += 8) {
    float4 eb[8]; unsigned vr[8];
    #pragma unroll
    for (int q = 0; q < 8; ++q) { int j = i + q; eb[q] = ebuf[(j < en) ? j : st]; }
    #pragma unroll
    for (int q = 0; q < 8; ++q) vr[q] = v1b[(size_t)__float_as_int(eb[q].x)*64 + lane];
    #pragma unroll
    for (int q = 0; q < 8; ++q) {
      bool ok = (i + q) < en;
      float s = head ? eb[q].z : eb[q].y;
      float e = ok ? __expf(s - m) : 0.f;
      den += e;
      alo = fmaf(e, __uint_as_float(vr[q] << 16),         alo);
      ahi = fmaf(e, __uint_as_float(vr[q] & 0xFFFF0000u), ahi);
    }
  }
  float inv = 1.f / (den + 1e-9f);   // final layer: NO leaky
  float hlo = alo*inv, hhi = ahi*inv;
  const float2* fw2 = reinterpret_cast<const float2*>(fcW);
  float2 f0 = fw2[2*lane], f1 = fw2[2*lane + 1];   // rows 2l, 2l+1 of fcW[128][2]
  float p0 = hlo*f0.x + hhi*f1.x;
  float p1 = hlo*f0.y + hhi*f1.y;
  #pragma unroll
  for (int o = 32; o > 0; o >>= 1) {
    p0 += __shfl_down(p0, o);
    p1 += __shfl_down(p1, o);
  }
  if (lane == 0) {
    pnode[n*2]   = p0;
    pnode[n*2+1] = p1;
  }
}

// ---------------- graph readout: segmented sum over sorted gid, few atomics ----------------
__global__ __launch_bounds__(256) void gsum_k(const float* __restrict__ pnode, const int* __restrict__ gid,
                                              float* __restrict__ out) {
  int n = blockIdx.x*256 + threadIdx.x;
  int lane = threadIdx.x & 63;
  bool ok = n < NN;
  int g = ok ? gid[n] : -1;
  float p0 = ok ? pnode[n*2]   : 0.f;
  float p1 = ok ? pnode[n*2+1] : 0.f;
  #pragma unroll
  for (int o = 1; o < 64; o <<= 1) {
    int pg = __shfl_down(g, o);
    float q0 = __shfl_down(p0, o);
    float q1 = __shfl_down(p1, o);
    if ((lane + o) < 64 && pg == g) { p0 += q0; p1 += q1; }  // clamp: sum is NOT idempotent
  }
  int prev = __shfl_up(g, 1);
  if (ok && (lane == 0 || prev != g)) {
    atomicAdd(&out[g*2],     p0);
    atomicAdd(&out[g*2 + 1], p1);
  }
}

extern "C" void kernel_launch(void* const* d_in, const int* in_sizes, int n_in,
                              void* d_out, int out_size, void* d_ws, size_t ws_size,
                              hipStream_t stream) {
  const float* nt  = (const float*)d_in[0];
  const float* nl  = (const float*)d_in[1];
  const float* xe  = (const float*)d_in[2];
  const int*   src = (const int*)d_in[3];
  const int*   dst = (const int*)d_in[4];
  const int*   gid = (const int*)d_in[5];
  const float* Wn0 = (const float*)d_in[6],  *bn0 = (const float*)d_in[7];
  const float* Wv0 = (const float*)d_in[8],  *bv0 = (const float*)d_in[9];
  const float* We0 = (const float*)d_in[10], *be0 = (const float*)d_in[11];
  const float* as0 = (const float*)d_in[12], *ae0 = (const float*)d_in[13];
  const float* ad0 = (const float*)d_in[14], *ab0 = (const float*)d_in[15];
  const float* Wn1 = (const float*)d_in[16], *bn1 = (const float*)d_in[17];
  const float* Wv1 = (const float*)d_in[18], *bv1 = (const float*)d_in[19];
  const float* We1 = (const float*)d_in[20], *be1 = (const float*)d_in[21];
  const float* as1 = (const float*)d_in[22], *ae1 = (const float*)d_in[23];
  const float* ad1 = (const float*)d_in[24], *ab1 = (const float*)d_in[25];
  const float* fcW = (const float*)d_in[26], *fcb = (const float*)d_in[27];
  float* out = (float*)d_out;

  // workspace layout (floats, then uints, then ints); ~122 MB
  float* fold  = (float*)d_ws;                        // 4096
  float* zs    = fold + FOLD_FLOATS;                  // N*2 (layer0 then layer1)
  float* zd    = zs + (size_t)NN*2;                   // N*2
  unsigned* v0b = (unsigned*)(zd + (size_t)NN*2);     // N*64 u32 (bf16 x2)
  unsigned* v1b = v0b + (size_t)NN*64;                // N*64 u32
  unsigned* xb  = v1b + (size_t)NN*64;                // N*64 u32 (normalized l0 output)
  unsigned* w1tw = xb + (size_t)NN*64;                // 128*64 u32 (bf16 W1^T)
  float* et1p  = (float*)(w1tw + 128*64);             // E*2
  float* ebuff = et1p + (size_t)EE*2;                 // E*4 (float4 per CSR pos)
  unsigned* menc0 = (unsigned*)(ebuff + (size_t)EE*4); // N*2
  unsigned* menc1 = menc0 + (size_t)NN*2;             // N*2
  float* pnode = (float*)(menc1 + (size_t)NN*2);      // N*2
  int* cnt    = (int*)(pnode + (size_t)NN*2);         // N
  int* off    = cnt + NN;                             // N+1
  int* cursor = off + NN + 1;                         // N
  int* eid    = cursor + NN;                          // E
  int* part   = eid + EE;                             // NCH
  float4* ebuf = (float4*)ebuff;

  hipMemsetAsync(cnt, 0, NN*sizeof(int), stream);
  hipMemsetAsync(menc0, 0, (size_t)NN*4*sizeof(unsigned), stream);  // menc0 + menc1
  fold_k<<<1, 256, 0, stream>>>(Wn0, bn0, as0, ad0, We0, We1, be1, ae1, Wn1, bn1, as1, ad1, Wv1, fold, w1tw);
  count_k<<<EE/256, 256, 0, stream>>>(dst, cnt);
  scan1_k<<<NCH, 1024, 0, stream>>>(cnt, part);
  scan2_k<<<1, 1, 0, stream>>>(part, off);
  scan3_k<<<NCH, 1024, 0, stream>>>(cnt, part, off, cursor);
  scatter_k<<<EE/256, 256, 0, stream>>>(dst, cursor, eid);
  node0v_k<<<NN/8, 128, 0, stream>>>(nt, nl, Wv0, bv0, v0b);
  nodez_k<<<(NN + 255)/256, 256, 0, stream>>>(nt, nl, fold, zs, zd);
  edge0_k<<<EE/256, 256, 0, stream>>>(xe, src, dst, eid, be0, ae0, ab0, fold, zs, zd, ebuf, et1p, menc0);
  agg0_k<<<NN/4, 256, 0, stream>>>(off, ebuf, menc0, v0b, fold, xb, zs, zd);
  node1m_k<<<(NN/16 + 3)/4, 256, 0, stream>>>(xb, w1tw, bv1, (unsigned short*)v1b);
  edge1_k<<<EE/256, 256, 0, stream>>>(ebuf, zs, zd, et1p, ab1, menc1);
  outinit_k<<<1, 128, 0, stream>>>(fcb, out);
  agg1_k<<<NN/4, 256, 0, stream>>>(off, ebuf, menc1, v1b, fcW, pnode);
  gsum_k<<<(NN + 255)/256, 256, 0, stream>>>(pnode, gid, out);
}

// Round 9
// 479.128 us; speedup vs baseline: 1.5936x; 1.3495x over previous
//
#include <hip/hip_runtime.h>

#define NN 100000
#define EE 1600000
#define NG 64

// binned CSR build
#define BSH 9
#define NWIN 512          // 1<<BSH nodes per bucket
#define NB 196            // ceil(NN/NWIN)
#define CAP 10240         // max edges per bucket (mean 8192, sigma ~91)
#define EPB 4096          // edges per binA block

// fold-area float offsets
#define OFF_WS0 0
#define OFF_WD0 128
#define OFF_CS0 256
#define OFF_CD0 258
#define OFF_U1  260
#define OFF_C1  324
#define OFF_WS1 512
#define OFF_WD1 768
#define OFF_CS1 1024
#define OFF_CD1 1026
#define OFF_WT0 2048   // transposed We0: [32 out][32 in]
#define FOLD_FLOATS 4096

typedef __attribute__((ext_vector_type(8))) short short8;
typedef __attribute__((ext_vector_type(4))) float f32x4;

__device__ __forceinline__ unsigned encm(float f) {
  unsigned u = __float_as_uint(f);
  return (u & 0x80000000u) ? ~u : (u | 0x80000000u);
}
__device__ __forceinline__ float decm(unsigned u) {
  return (u & 0x80000000u) ? __uint_as_float(u & 0x7FFFFFFFu) : __uint_as_float(~u);
}
__device__ __forceinline__ unsigned bf16r(float f) {   // round-to-nearest-even bf16 bits
  unsigned u = __float_as_uint(f);
  return (u + 0x7FFFu + ((u >> 16) & 1u)) >> 16;
}

// ---------------- fold: contracted weight vectors, We0 transpose, Wv1 bf16-transpose ----------------
__global__ void fold_k(const float* __restrict__ Wn0, const float* __restrict__ bn0,
                       const float* __restrict__ as0, const float* __restrict__ ad0,
                       const float* __restrict__ We0,
                       const float* __restrict__ We1, const float* __restrict__ be1,
                       const float* __restrict__ ae1,
                       const float* __restrict__ Wn1, const float* __restrict__ bn1,
                       const float* __restrict__ as1, const float* __restrict__ ad1,
                       const float* __restrict__ Wv1,
                       float* __restrict__ fold, unsigned* __restrict__ w1tw) {
  int t = threadIdx.x;  // 256
  for (int i = t; i < 128; i += 256) {        // ws0/wd0: Wn0[2,64,32] . a[2,32]
    int h = i >> 6, d = i & 63;
    float s = 0.f, sd = 0.f;
    for (int k = 0; k < 32; ++k) {
      float w = Wn0[h*2048 + d*32 + k];
      s  += w * as0[h*32 + k];
      sd += w * ad0[h*32 + k];
    }
    fold[OFF_WS0 + i] = s; fold[OFF_WD0 + i] = sd;
  }
  for (int i = t; i < 64; i += 256) {         // u1: We1[2,32,16] . ae1[2,16]
    int h = i >> 5, d = i & 31;
    float s = 0.f;
    for (int k = 0; k < 16; ++k) s += We1[h*512 + d*16 + k] * ae1[h*16 + k];
    fold[OFF_U1 + i] = s;
  }
  for (int i = t; i < 1024; i += 256) {       // WT0[o][d] = We0[o>>4][d][o&15]
    int o = i >> 5, d = i & 31;
    fold[OFF_WT0 + o*32 + d] = We0[(o >> 4)*512 + d*16 + (o & 15)];
  }
  // w1tw: bf16 W1^T, ushort layout wt[o][d] packed as u32 words: word idx = o*64 + d/2
  for (int i = t; i < 8192; i += 256) {
    int o = i >> 6, dw = i & 63;
    int d0 = 2*dw, d1 = d0 + 1;
    float f0 = Wv1[(o >> 6)*8192 + d0*64 + (o & 63)];
    float f1 = Wv1[(o >> 6)*8192 + d1*64 + (o & 63)];
    w1tw[i] = bf16r(f0) | (bf16r(f1) << 16);
  }
  if (t < 256) {                              // ws1/wd1: Wn1[2,128,32] . a[2,32]
    int i = t, h = i >> 7, d = i & 127;
    float s = 0.f, sd = 0.f;
    for (int k = 0; k < 32; ++k) {
      float w = Wn1[h*4096 + d*32 + k];
      s  += w * as1[h*32 + k];
      sd += w * ad1[h*32 + k];
    }
    fold[OFF_WS1 + i] = s; fold[OFF_WD1 + i] = sd;
  }
  if (t < 2) {
    float cs = 0.f, cd = 0.f;
    for (int k = 0; k < 32; ++k) { cs += bn0[t*32+k]*as0[t*32+k]; cd += bn0[t*32+k]*ad0[t*32+k]; }
    fold[OFF_CS0 + t] = cs; fold[OFF_CD0 + t] = cd;
    float c1 = 0.f;
    for (int k = 0; k < 16; ++k) c1 += ae1[t*16+k]*be1[t*16+k];
    fold[OFF_C1 + t] = c1;
    float cs1 = 0.f, cd1 = 0.f;
    for (int k = 0; k < 32; ++k) { cs1 += bn1[t*32+k]*as1[t*32+k]; cd1 += bn1[t*32+k]*ad1[t*32+k]; }
    fold[OFF_CS1 + t] = cs1; fold[OFF_CD1 + t] = cd1;
  }
}

// ---------------- binned CSR build, phase A: bin (e,dn) into 196 coarse buckets ----------------
__global__ __launch_bounds__(256) void binA_k(const int* __restrict__ dst,
                                              int* __restrict__ bcur, uint2* __restrict__ stg) {
  __shared__ int hist[NB], gbase[NB];
  int tid = threadIdx.x;
  for (int i = tid; i < NB; i += 256) hist[i] = 0;
  __syncthreads();
  int e0 = blockIdx.x*EPB;
  int dd[16], li[16];
  #pragma unroll
  for (int q = 0; q < 16; ++q) {
    int e = e0 + q*256 + tid;
    if (e < EE) {
      int dn = dst[e];
      dd[q] = dn;
      li[q] = atomicAdd(&hist[dn >> BSH], 1);
    }
  }
  __syncthreads();
  if (tid < NB) gbase[tid] = atomicAdd(&bcur[tid], hist[tid]);
  __syncthreads();
  #pragma unroll
  for (int q = 0; q < 16; ++q) {
    int e = e0 + q*256 + tid;
    if (e < EE) {
      int b = dd[q] >> BSH;
      int idx = gbase[b] + li[q];
      if (idx < CAP) stg[(size_t)b*CAP + idx] = make_uint2((unsigned)e, (unsigned)dd[q]);
    }
  }
}

__global__ void scanB_k(const int* __restrict__ bcur, int* __restrict__ bbase) {  // <<<1,1>>>
  int s = 0;
  for (int b = 0; b < NB; ++b) { bbase[b] = s; s += bcur[b]; }
}

// ---------------- phase B: per-bucket local count/scan -> off[], place eid/dnp in CSR window ----------------
__global__ __launch_bounds__(256) void binB_k(const uint2* __restrict__ stg, const int* __restrict__ bcur,
                                              const int* __restrict__ bbase,
                                              int* __restrict__ off, int* __restrict__ eid,
                                              int* __restrict__ dnp) {
  __shared__ int hist[NWIN], curx[NWIN], wsum[4];
  int tid = threadIdx.x, lane = tid & 63, w = tid >> 6;
  int b = blockIdx.x;
  int nbase = b << BSH;
  int cnt = bcur[b], base = bbase[b];
  for (int i = tid; i < NWIN; i += 256) hist[i] = 0;
  __syncthreads();
  const uint2* sp = stg + (size_t)b*CAP;
  for (int i = tid; i < cnt; i += 256) atomicAdd(&hist[sp[i].y - nbase], 1);
  __syncthreads();
  // exclusive scan over 512 counts (2 per thread)
  int a0 = hist[2*tid], a1 = hist[2*tid + 1];
  int tsum = a0 + a1;
  int x = tsum;
  #pragma unroll
  for (int o = 1; o < 64; o <<= 1) { int y = __shfl_up(x, o); if (lane >= o) x += y; }
  if (lane == 63) wsum[w] = x;
  __syncthreads();
  if (tid == 0) { int s = 0; for (int q = 0; q < 4; ++q) { int t = wsum[q]; wsum[q] = s; s += t; } }
  __syncthreads();
  int excl = wsum[w] + x - tsum;
  curx[2*tid]     = base + excl;
  curx[2*tid + 1] = base + excl + a0;
  __syncthreads();
  for (int j = tid; j < NWIN; j += 256) {
    int n = nbase + j;
    if (n < NN) off[n] = curx[j];
  }
  if (b == NB - 1 && tid == 0) off[NN] = base + cnt;
  __syncthreads();
  for (int i = tid; i < cnt; i += 256) {
    uint2 r = sp[i];
    int p = atomicAdd(&curx[r.y - nbase], 1);
    eid[p] = (int)r.x;
    dnp[p] = (int)r.y;
  }
}

// ---------------- layer-0 v-projection: W in VGPRs, 8 nodes/block, bf16 packed output ----------------
__global__ __launch_bounds__(128) void node0v_k(const float* __restrict__ nt, const float* __restrict__ nl,
                                                const float* __restrict__ Wv0, const float* __restrict__ bv0,
                                                unsigned* __restrict__ v0b) {
  int tid = threadIdx.x;
  int h = tid >> 6, k = tid & 63;
  int sl2 = k & 31;
  float w[64];
  #pragma unroll
  for (int d = 0; d < 64; ++d) w[d] = Wv0[h*4096 + d*64 + k];
  float b = bv0[tid];
  int nb = blockIdx.x * 8;   // grid 12500 * 8 = 100000 exactly
  #pragma unroll 1
  for (int r = 0; r < 8; ++r) {
    int n = nb + r;
    const float* nrow = nt + (size_t)n*14;   // uniform addresses -> SGPR loads
    const float* lrow = nl + (size_t)n*50;
    float acc = b;
    #pragma unroll
    for (int d = 0; d < 14; ++d) acc = fmaf(nrow[d], w[d], acc);
    #pragma unroll
    for (int d = 0; d < 50; ++d) acc = fmaf(lrow[d], w[14 + d], acc);
    float p0 = __shfl(acc, 2*sl2);
    float p1 = __shfl(acc, 2*sl2 + 1);
    if (k < 32) v0b[(size_t)n*64 + h*32 + sl2] = bf16r(p0) | (bf16r(p1) << 16);
  }
}

// ---------------- layer-0 z-scalars: one thread per node ----------------
__global__ __launch_bounds__(256) void nodez_k(const float* __restrict__ nt, const float* __restrict__ nl,
                                               const float* __restrict__ fold,
                                               float* __restrict__ zs0, float* __restrict__ zd0) {
  int n = blockIdx.x*256 + threadIdx.x;
  if (n >= NN) return;
  float p0 = 0.f, p1 = 0.f, p2 = 0.f, p3 = 0.f;
  #pragma unroll
  for (int d = 0; d < 64; ++d) {
    float x = (d < 14) ? nt[(size_t)n*14 + d] : nl[(size_t)n*50 + d - 14];
    p0 = fmaf(x, fold[OFF_WS0 + d],      p0);
    p1 = fmaf(x, fold[OFF_WS0 + 64 + d], p1);
    p2 = fmaf(x, fold[OFF_WD0 + d],      p2);
    p3 = fmaf(x, fold[OFF_WD0 + 64 + d], p3);
  }
  zs0[n*2]   = p0 + fold[OFF_CS0];
  zs0[n*2+1] = p1 + fold[OFF_CS0+1];
  zd0[n*2]   = p2 + fold[OFF_CD0];
  zd0[n*2+1] = p3 + fold[OFF_CD0+1];
}

// ---------------- layer-0 edge pass (CSR order): uniform-W MLP, coalesced dnp, segmented max ----------------
__global__ __launch_bounds__(256) void edge0_k(const float* __restrict__ xe,
                                               const int* __restrict__ src,
                                               const int* __restrict__ eid, const int* __restrict__ dnp,
                                               const float* __restrict__ be0,
                                               const float* __restrict__ ae0, const float* __restrict__ ab0,
                                               const float* __restrict__ fold,
                                               const float* __restrict__ zs0, const float* __restrict__ zd0,
                                               float4* __restrict__ ebuf, float* __restrict__ et1p,
                                               unsigned* __restrict__ menc0) {
  int p = blockIdx.x*256 + threadIdx.x;   // grid exact: EE/256
  int lane = threadIdx.x & 63;
  int e = eid[p];
  int dn = dnp[p];
  int sn = src[e];
  const float4* xp = reinterpret_cast<const float4*>(xe + (size_t)e*32);
  float4 xv[8];
  #pragma unroll
  for (int q = 0; q < 8; ++q) xv[q] = xp[q];
  const float* WT = fold + OFF_WT0;
  const float* U1 = fold + OFF_U1;
  float s0 = 0.f, s1 = 0.f, etA = 0.f, etB = 0.f;
  #pragma unroll 4
  for (int o = 0; o < 16; ++o) {          // head 0
    float acc = be0[o];
    #pragma unroll
    for (int q = 0; q < 8; ++q) {         // WT row: wave-uniform -> SGPR loads
      float4 w = *reinterpret_cast<const float4*>(WT + o*32 + q*4);
      acc = fmaf(xv[q].x, w.x, acc); acc = fmaf(xv[q].y, w.y, acc);
      acc = fmaf(xv[q].z, w.z, acc); acc = fmaf(xv[q].w, w.w, acc);
    }
    s0 = fmaf(ae0[o], acc, s0);
    float lz = acc >= 0.f ? acc : 0.01f*acc;
    etA = fmaf(lz, U1[o], etA); etB = fmaf(lz, U1[32 + o], etB);
  }
  #pragma unroll 4
  for (int o = 16; o < 32; ++o) {         // head 1
    float acc = be0[o];
    #pragma unroll
    for (int q = 0; q < 8; ++q) {
      float4 w = *reinterpret_cast<const float4*>(WT + o*32 + q*4);
      acc = fmaf(xv[q].x, w.x, acc); acc = fmaf(xv[q].y, w.y, acc);
      acc = fmaf(xv[q].z, w.z, acc); acc = fmaf(xv[q].w, w.w, acc);
    }
    s1 = fmaf(ae0[o], acc, s1);
    float lz = acc >= 0.f ? acc : 0.01f*acc;
    etA = fmaf(lz, U1[o], etA); etB = fmaf(lz, U1[32 + o], etB);
  }
  float2 zsv = *reinterpret_cast<const float2*>(zs0 + (size_t)sn*2);
  float2 zdv = *reinterpret_cast<const float2*>(zd0 + (size_t)dn*2);
  float l0 = zsv.x + s0 + zdv.x + ab0[0];
  float l1 = zsv.y + s1 + zdv.y + ab0[1];
  l0 = l0 >= 0.f ? l0 : 0.2f*l0;
  l1 = l1 >= 0.f ? l1 : 0.2f*l1;
  ebuf[p] = make_float4(__int_as_float(sn), l0, l1, __int_as_float(dn));
  *reinterpret_cast<float2*>(et1p + (size_t)p*2) =
      make_float2(etA + fold[OFF_C1], etB + fold[OFF_C1+1]);
  // segmented max over sorted dn
  unsigned e0 = encm(l0), e1 = encm(l1);
  #pragma unroll
  for (int o = 1; o < 64; o <<= 1) {      // max idempotent: wave-edge self-return safe
    int pdn = __shfl_down(dn, o);
    unsigned q0 = __shfl_down(e0, o);
    unsigned q1 = __shfl_down(e1, o);
    if (pdn == dn) { e0 = max(e0, q0); e1 = max(e1, q1); }
  }
  int prev = __shfl_up(dn, 1);
  if (lane == 0 || prev != dn) {
    atomicMax(&menc0[(size_t)dn*2],   e0);
    atomicMax(&menc0[(size_t)dn*2+1], e1);
  }
}

// ---------------- layer-0 aggregate: 1 node/wave, lane owns dims (2l,2l+1), no reduction ----------------
__global__ __launch_bounds__(256) void agg0_k(const int* __restrict__ off,
                                              const float4* __restrict__ ebuf,
                                              const unsigned* __restrict__ menc,
                                              const unsigned* __restrict__ v0b,
                                              const float* __restrict__ fold,
                                              unsigned* __restrict__ xb,
                                              float* __restrict__ zs1, float* __restrict__ zd1) {
  int tid = threadIdx.x, w = tid >> 6, lane = tid & 63;
  int n = blockIdx.x*4 + w;            // grid 25000 * 4 waves = 100000 exactly
  int head = lane >> 5;                // lane's dims 2l,2l+1 -> head = l>>5
  int st = off[n], en = off[n+1];
  float m = decm(menc[(size_t)n*2 + head]);
  float alo = 0.f, ahi = 0.f, den = 0.f;
  for (int i = st; i < en; i += 8) {
    float4 eb[8]; unsigned vr[8];
    #pragma unroll
    for (int q = 0; q < 8; ++q) { int j = i + q; eb[q] = ebuf[(j < en) ? j : st]; }
    #pragma unroll
    for (int q = 0; q < 8; ++q) vr[q] = v0b[(size_t)__float_as_int(eb[q].x)*64 + lane];
    #pragma unroll
    for (int q = 0; q < 8; ++q) {
      bool ok = (i + q) < en;
      float s = head ? eb[q].z : eb[q].y;
      float e = ok ? __expf(s - m) : 0.f;
      den += e;
      alo = fmaf(e, __uint_as_float(vr[q] << 16),         alo);
      ahi = fmaf(e, __uint_as_float(vr[q] & 0xFFFF0000u), ahi);
    }
  }
  float inv = 1.f / (den + 1e-9f);
  float xlo = alo*inv, xhi = ahi*inv;
  xlo = xlo >= 0.f ? xlo : 0.01f*xlo;   // inter-layer leaky
  xhi = xhi >= 0.f ? xhi : 0.01f*xhi;
  xb[(size_t)n*64 + lane] = bf16r(xlo) | (bf16r(xhi) << 16);
  // zs1/zd1 scalars: 4 dots over 128 dims, lane holds 2
  const float2* ws1 = reinterpret_cast<const float2*>(fold + OFF_WS1);
  const float2* wd1 = reinterpret_cast<const float2*>(fold + OFF_WD1);
  float2 wa = ws1[lane], wb = ws1[64 + lane], wc = wd1[lane], wd = wd1[64 + lane];
  float p0 = xlo*wa.x + xhi*wa.y;
  float p1 = xlo*wb.x + xhi*wb.y;
  float p2 = xlo*wc.x + xhi*wc.y;
  float p3 = xlo*wd.x + xhi*wd.y;
  #pragma unroll
  for (int o = 32; o > 0; o >>= 1) {
    p0 += __shfl_down(p0, o); p1 += __shfl_down(p1, o);
    p2 += __shfl_down(p2, o); p3 += __shfl_down(p3, o);
  }
  if (lane == 0) {
    zs1[n*2]   = p0 + fold[OFF_CS1];
    zs1[n*2+1] = p1 + fold[OFF_CS1+1];
    zd1[n*2]   = p2 + fold[OFF_CD1];
    zd1[n*2+1] = p3 + fold[OFF_CD1+1];
  }
}

// ---------------- layer-1 node MLP via MFMA: [N,128]bf16 @ [128,128]bf16 -> v1 bf16 ----------------
__global__ __launch_bounds__(256) void node1m_k(const unsigned* __restrict__ xb,
                                                const unsigned* __restrict__ w1tw,
                                                const float* __restrict__ bv1,
                                                unsigned short* __restrict__ v1s) {
  int tid = threadIdx.x, w = tid >> 6, lane = tid & 63;
  int tile = blockIdx.x*4 + w;         // 6250 tiles of 16 nodes
  if (tile >= NN/16) return;
  int row = lane & 15, kg = lane >> 4;
  int n = tile*16 + row;
  short8 a[4];
  #pragma unroll
  for (int ks = 0; ks < 4; ++ks)
    a[ks] = *reinterpret_cast<const short8*>(xb + (size_t)n*64 + ks*16 + kg*4);
  #pragma unroll 2
  for (int t = 0; t < 8; ++t) {
    float bias = bv1[t*16 + row];      // out col o = t*16 + (lane&15)
    f32x4 acc = {bias, bias, bias, bias};
    #pragma unroll
    for (int ks = 0; ks < 4; ++ks) {
      short8 b = *reinterpret_cast<const short8*>(w1tw + (size_t)(t*16 + row)*64 + ks*16 + kg*4);
      acc = __builtin_amdgcn_mfma_f32_16x16x32_bf16(a[ks], b, acc, 0, 0, 0);
    }
    int o = t*16 + row;
    #pragma unroll
    for (int r = 0; r < 4; ++r) {
      int nr = tile*16 + kg*4 + r;
      v1s[(size_t)nr*128 + o] = (unsigned short)bf16r(acc[r]);
    }
  }
}

// ---------------- layer-1 edge logits + fused segmented max (dn from ebuf.w, sorted) ----------------
__global__ __launch_bounds__(256) void edge1_k(float4* __restrict__ ebuf,
                                               const float* __restrict__ zs1, const float* __restrict__ zd1,
                                               const float* __restrict__ et1p, const float* __restrict__ ab1,
                                               unsigned* __restrict__ menc1) {
  int i = blockIdx.x*256 + threadIdx.x;
  int lane = threadIdx.x & 63;
  bool ok = i < EE;
  float l0 = 0.f, l1 = 0.f; int dn = -1;
  if (ok) {
    float4 eb = ebuf[i];
    int sn = __float_as_int(eb.x);
    dn = __float_as_int(eb.w);
    float2 et = *reinterpret_cast<const float2*>(et1p + (size_t)i*2);
    l0 = zs1[sn*2]   + et.x + zd1[dn*2]   + ab1[0];
    l1 = zs1[sn*2+1] + et.y + zd1[dn*2+1] + ab1[1];
    l0 = l0 >= 0.f ? l0 : 0.2f*l0;
    l1 = l1 >= 0.f ? l1 : 0.2f*l1;
    eb.y = l0; eb.z = l1;
    ebuf[i] = eb;
  }
  unsigned e0 = ok ? encm(l0) : 0u;
  unsigned e1 = ok ? encm(l1) : 0u;
  #pragma unroll
  for (int o = 1; o < 64; o <<= 1) {   // max is idempotent: shfl self-return at wave edge is safe
    int pdn = __shfl_down(dn, o);
    unsigned q0 = __shfl_down(e0, o);
    unsigned q1 = __shfl_down(e1, o);
    if (pdn == dn) { e0 = max(e0, q0); e1 = max(e1, q1); }
  }
  int prev = __shfl_up(dn, 1);
  if (ok && (lane == 0 || prev != dn)) {
    atomicMax(&menc1[(size_t)dn*2],   e0);
    atomicMax(&menc1[(size_t)dn*2+1], e1);
  }
}

__global__ void outinit_k(const float* __restrict__ fcb, float* __restrict__ out) {
  int i = threadIdx.x;  // 128
  out[i] = fcb[i & 1];
}

// ---------------- layer-1 aggregate: 1 node/wave, lane owns dims, fused FC ----------------
__global__ __launch_bounds__(256) void agg1_k(const int* __restrict__ off,
                                              const float4* __restrict__ ebuf,
                                              const unsigned* __restrict__ menc,
                                              const unsigned* __restrict__ v1b,
                                              const float* __restrict__ fcW,
                                              float* __restrict__ pnode) {
  int tid = threadIdx.x, w = tid >> 6, lane = tid & 63;
  int n = blockIdx.x*4 + w;
  int head = lane >> 5;
  int st = off[n], en = off[n+1];
  float m = decm(menc[(size_t)n*2 + head]);
  float alo = 0.f, ahi = 0.f, den = 0.f;
  for (int i = st; i < en; i += 8) {
    float4 eb[8]; unsigned vr[8];
    #pragma unroll
    for (int q = 0; q < 8; ++q) { int j = i + q; eb[q] = ebuf[(j < en) ? j : st]; }
    #pragma unroll
    for (int q = 0; q < 8; ++q) vr[q] = v1b[(size_t)__float_as_int(eb[q].x)*64 + lane];
    #pragma unroll
    for (int q = 0; q < 8; ++q) {
      bool ok = (i + q) < en;
      float s = head ? eb[q].z : eb[q].y;
      float e = ok ? __expf(s - m) : 0.f;
      den += e;
      alo = fmaf(e, __uint_as_float(vr[q] << 16),         alo);
      ahi = fmaf(e, __uint_as_float(vr[q] & 0xFFFF0000u), ahi);
    }
  }
  float inv = 1.f / (den + 1e-9f);   // final layer: NO leaky
  float hlo = alo*inv, hhi = ahi*inv;
  const float2* fw2 = reinterpret_cast<const float2*>(fcW);
  float2 f0 = fw2[2*lane], f1 = fw2[2*lane + 1];   // rows 2l, 2l+1 of fcW[128][2]
  float p0 = hlo*f0.x + hhi*f1.x;
  float p1 = hlo*f0.y + hhi*f1.y;
  #pragma unroll
  for (int o = 32; o > 0; o >>= 1) {
    p0 += __shfl_down(p0, o);
    p1 += __shfl_down(p1, o);
  }
  if (lane == 0) {
    pnode[n*2]   = p0;
    pnode[n*2+1] = p1;
  }
}

// ---------------- graph readout: segmented sum over sorted gid, few atomics ----------------
__global__ __launch_bounds__(256) void gsum_k(const float* __restrict__ pnode, const int* __restrict__ gid,
                                              float* __restrict__ out) {
  int n = blockIdx.x*256 + threadIdx.x;
  int lane = threadIdx.x & 63;
  bool ok = n < NN;
  int g = ok ? gid[n] : -1;
  float p0 = ok ? pnode[n*2]   : 0.f;
  float p1 = ok ? pnode[n*2+1] : 0.f;
  #pragma unroll
  for (int o = 1; o < 64; o <<= 1) {
    int pg = __shfl_down(g, o);
    float q0 = __shfl_down(p0, o);
    float q1 = __shfl_down(p1, o);
    if ((lane + o) < 64 && pg == g) { p0 += q0; p1 += q1; }  // clamp: sum is NOT idempotent
  }
  int prev = __shfl_up(g, 1);
  if (ok && (lane == 0 || prev != g)) {
    atomicAdd(&out[g*2],     p0);
    atomicAdd(&out[g*2 + 1], p1);
  }
}

extern "C" void kernel_launch(void* const* d_in, const int* in_sizes, int n_in,
                              void* d_out, int out_size, void* d_ws, size_t ws_size,
                              hipStream_t stream) {
  const float* nt  = (const float*)d_in[0];
  const float* nl  = (const float*)d_in[1];
  const float* xe  = (const float*)d_in[2];
  const int*   src = (const int*)d_in[3];
  const int*   dst = (const int*)d_in[4];
  const int*   gid = (const int*)d_in[5];
  const float* Wn0 = (const float*)d_in[6],  *bn0 = (const float*)d_in[7];
  const float* Wv0 = (const float*)d_in[8],  *bv0 = (const float*)d_in[9];
  const float* We0 = (const float*)d_in[10], *be0 = (const float*)d_in[11];
  const float* as0 = (const float*)d_in[12], *ae0 = (const float*)d_in[13];
  const float* ad0 = (const float*)d_in[14], *ab0 = (const float*)d_in[15];
  const float* Wn1 = (const float*)d_in[16], *bn1 = (const float*)d_in[17];
  const float* Wv1 = (const float*)d_in[18], *bv1 = (const float*)d_in[19];
  const float* We1 = (const float*)d_in[20], *be1 = (const float*)d_in[21];
  const float* as1 = (const float*)d_in[22], *ae1 = (const float*)d_in[23];
  const float* ad1 = (const float*)d_in[24], *ab1 = (const float*)d_in[25];
  const float* fcW = (const float*)d_in[26], *fcb = (const float*)d_in[27];
  float* out = (float*)d_out;

  // workspace layout; ~149 MB
  float* fold  = (float*)d_ws;                        // 4096
  float* zs    = fold + FOLD_FLOATS;                  // N*2 (layer0 then layer1)
  float* zd    = zs + (size_t)NN*2;                   // N*2
  unsigned* v0b = (unsigned*)(zd + (size_t)NN*2);     // N*64 u32 (bf16 x2)
  unsigned* v1b = v0b + (size_t)NN*64;                // N*64 u32
  unsigned* xb  = v1b + (size_t)NN*64;                // N*64 u32 (normalized l0 output)
  unsigned* w1tw = xb + (size_t)NN*64;                // 128*64 u32 (bf16 W1^T)
  float* et1p  = (float*)(w1tw + 128*64);             // E*2
  float* ebuff = et1p + (size_t)EE*2;                 // E*4 (float4 per CSR pos)
  unsigned* menc0 = (unsigned*)(ebuff + (size_t)EE*4); // N*2  -- memset region start
  unsigned* menc1 = menc0 + (size_t)NN*2;             // N*2
  int* bcur   = (int*)(menc1 + (size_t)NN*2);         // NB   -- memset region end
  int* bbase  = bcur + NB;                            // NB
  float* pnode = (float*)(bbase + NB);                // N*2
  int* off    = (int*)(pnode + (size_t)NN*2);         // N+1
  int* eid    = off + NN + 1;                         // E
  int* dnp    = eid + EE;                             // E
  uint2* stg  = (uint2*)(dnp + EE);                   // NB*CAP uint2 (~16 MB)
  float4* ebuf = (float4*)ebuff;

  hipMemsetAsync(menc0, 0, ((size_t)NN*4 + NB)*sizeof(unsigned), stream);  // menc0+menc1+bcur
  fold_k<<<1, 256, 0, stream>>>(Wn0, bn0, as0, ad0, We0, We1, be1, ae1, Wn1, bn1, as1, ad1, Wv1, fold, w1tw);
  binA_k<<<(EE + EPB - 1)/EPB, 256, 0, stream>>>(dst, bcur, stg);
  scanB_k<<<1, 1, 0, stream>>>(bcur, bbase);
  binB_k<<<NB, 256, 0, stream>>>(stg, bcur, bbase, off, eid, dnp);
  node0v_k<<<NN/8, 128, 0, stream>>>(nt, nl, Wv0, bv0, v0b);
  nodez_k<<<(NN + 255)/256, 256, 0, stream>>>(nt, nl, fold, zs, zd);
  edge0_k<<<EE/256, 256, 0, stream>>>(xe, src, eid, dnp, be0, ae0, ab0, fold, zs, zd, ebuf, et1p, menc0);
  agg0_k<<<NN/4, 256, 0, stream>>>(off, ebuf, menc0, v0b, fold, xb, zs, zd);
  node1m_k<<<(NN/16 + 3)/4, 256, 0, stream>>>(xb, w1tw, bv1, (unsigned short*)v1b);
  edge1_k<<<EE/256, 256, 0, stream>>>(ebuf, zs, zd, et1p, ab1, menc1);
  outinit_k<<<1, 128, 0, stream>>>(fcb, out);
  agg1_k<<<NN/4, 256, 0, stream>>>(off, ebuf, menc1, v1b, fcW, pnode);
  gsum_k<<<(NN + 255)/256, 256, 0, stream>>>(pnode, gid, out);
}